// Round 15
// baseline (284.027 us; speedup 1.0000x reference)
//
#include <hip/hip_runtime.h>
#include <math.h>
#include <stdint.h>

// BlindCrossAttention on MI355X (gfx950).
// Round 15 = Round 14 with xgemm DELETED: attn2 absorbs x = e1@pos (K-split
// across its 8 waves, LDS partial-reduce) and the att0 = e1*inv1 write
// (from the same e1 fragment loads). Saves a launch + xw round-trip.
// 7 launches.

typedef _Float16 f16;
typedef _Float16 f16x4 __attribute__((ext_vector_type(4)));
typedef _Float16 f16x8 __attribute__((ext_vector_type(8)));
typedef float f32x4 __attribute__((ext_vector_type(4)));

static constexpr int CB  = 4;
static constexpr int CNQ = 2048;
static constexpr int CNK = 2048;
static constexpr int CD  = 1024;
static constexpr int CP  = 64;

// ---------- async global->LDS, 16B/lane ----------
static __device__ __forceinline__ void async16(const f16* gp, f16* lp) {
  __builtin_amdgcn_global_load_lds(
      (const __attribute__((address_space(1))) void*)(uintptr_t)gp,
      (__attribute__((address_space(3))) void*)(uint32_t)(uintptr_t)lp,
      16, 0, 0);
}

// ---------- prep: pos table + cvt q,k -> f16 + transpose-cvt W's ----------
__global__ __launch_bounds__(256) void prep_kernel(
    const float* __restrict__ q, const float* __restrict__ k,
    const float* __restrict__ Wq, const float* __restrict__ Wk,
    const float* __restrict__ Wv,
    f16* __restrict__ q16, f16* __restrict__ k16,
    f16* __restrict__ WqT, f16* __restrict__ WkvT,
    f16* __restrict__ posb, f16* __restrict__ posTb) {
  const int b = blockIdx.x;
  if (b < 512) {                        // pos table
    int tid = b * 256 + threadIdx.x;
    int p = tid >> 11;
    int j = tid & (CNK - 1);
    int i = p & 31;
    float ph = (float)j * powf(10000.0f, -(float)i * (1.0f / 32.0f));
    float v = (p < 32) ? sinf(ph) : cosf(ph);
    posb[j * CP + p]   = (f16)v;
    posTb[p * CNK + j] = (f16)v;
  } else if (b < 512 + 16384) {         // cvt q,k
    const int NF4 = CB * CNQ * CD / 4;
    int tid = (b - 512) * 256 + threadIdx.x;
    const float* src = (tid < NF4) ? q : k;
    f16* dst = (tid < NF4) ? q16 : k16;
    int i = (tid < NF4) ? tid : tid - NF4;
    float4 v = reinterpret_cast<const float4*>(src)[i];
    f16x4 o = {(f16)v.x, (f16)v.y, (f16)v.z, (f16)v.w};
    reinterpret_cast<f16x4*>(dst)[i] = o;
  } else {                              // W -> WT f16
    __shared__ float t[64][65];
    const int idx = b - 16896;
    const int z = idx >> 8;
    const int rem = idx & 255;
    const float* W = (z == 0) ? Wq : (z == 1) ? Wk : Wv;
    f16* WT = (z == 0) ? WqT : (z == 1) ? WkvT : WkvT + 1024 * 1024;
    int k0 = (rem & 15) * 64, n0 = (rem >> 4) * 64;
    int tx = threadIdx.x & 63, ty = threadIdx.x >> 6;
#pragma unroll
    for (int i = 0; i < 16; i++)
      t[ty + 4 * i][tx] = W[(size_t)(k0 + ty + 4 * i) * CD + n0 + tx];
    __syncthreads();
#pragma unroll
    for (int i = 0; i < 16; i++)
      WT[(size_t)(n0 + 4 * i + ty) * CD + k0 + tx] = (f16)t[tx][ty + 4 * i];
  }
}

// ============ 2-barrier counted-prefetch dbuf GEMM core (wide waves) ============
template <int BM, int BN>
__device__ __forceinline__ void gemm_core2(
    const f16* __restrict__ Ab, const f16* __restrict__ Bb,
    int lda, int ldb, int K, int m0, int n0, f16* sm,
    f32x4 (&acc)[BM / 32][4]) {
  constexpr int FM = BM / 32;           // 4 or 8
  constexpr int TI = (BM + BN) / 64;    // 6 or 8
  constexpr int bufsz = (BM + BN) * 64;
  const int tid = threadIdx.x;
  const int lane = tid & 63, wid = tid >> 6;
  const int wr = wid >> 2, wc = wid & 3;
  const int lrow = lane & 15, kg = lane >> 4;

  auto stage = [&](int i, int kt, int buf) {
    const int s = i * 512 + tid;          // 16B slot
    const int row = s >> 3;
    const int cb = (s & 7) << 4;
    const int scb = cb ^ ((row & 7) << 4);  // pre-swizzled global source col
    const f16* src = (i < BM / 64)
        ? Ab + (size_t)(m0 + row) * lda + kt * 64 + (scb >> 1)
        : Bb + (size_t)(n0 + row - BM) * ldb + kt * 64 + (scb >> 1);
    async16(src, &sm[buf * bufsz + s * 8]);
  };

  const int NTk = K >> 6;
#pragma unroll
  for (int i = 0; i < TI; i++) stage(i, 0, 0);

  for (int t = 0; t < NTk; ++t) {
    const int cur = t & 1;
    if (t + 1 < NTk) {
#pragma unroll
      for (int i = 0; i < TI; i++) stage(i, t + 1, cur ^ 1);
      if constexpr (TI == 8) asm volatile("s_waitcnt vmcnt(8)" ::: "memory");
      else                   asm volatile("s_waitcnt vmcnt(6)" ::: "memory");
    } else {
      asm volatile("s_waitcnt vmcnt(0)" ::: "memory");
    }
    __builtin_amdgcn_s_barrier();        // tile t data ready in buf[cur]

    const f16* smA = sm + cur * bufsz;
    const f16* smB = smA + BM * 64;
    __builtin_amdgcn_s_setprio(1);
#pragma unroll
    for (int kk = 0; kk < 2; ++kk) {
      const int Cb = kk * 64 + kg * 16;
      f16x8 af[FM], bf[4];
#pragma unroll
      for (int m = 0; m < FM; ++m) {
        const int ar = wr * (BM / 2) + m * 16 + lrow;
        af[m] = *reinterpret_cast<const f16x8*>(
            &smA[ar * 64 + ((Cb ^ ((ar & 7) << 4)) >> 1)]);
      }
#pragma unroll
      for (int n = 0; n < 4; ++n) {
        const int br = wc * 64 + n * 16 + lrow;
        bf[n] = *reinterpret_cast<const f16x8*>(
            &smB[br * 64 + ((Cb ^ ((br & 7) << 4)) >> 1)]);
      }
#pragma unroll
      for (int m = 0; m < FM; ++m)
#pragma unroll
        for (int n = 0; n < 4; ++n)
          acc[m][n] = __builtin_amdgcn_mfma_f32_16x16x32_f16(af[m], bf[n], acc[m][n], 0, 0, 0);
    }
    __builtin_amdgcn_s_setprio(0);
    __builtin_amdgcn_s_barrier();        // all reads of buf[cur] done
  }
}

// ---------- epilogue: f16 store, LDS-staged ----------
template <int BM, int BN>
__device__ __forceinline__ void epi_f16(
    f32x4 (&acc)[BM / 32][4], f16* sm, f16* Cp, int ldc, int m0, int n0) {
  const int tid = threadIdx.x, lane = tid & 63, wid = tid >> 6;
  const int wr = wid >> 2, wc = wid & 3;
  const int rbase = wr * (BM / 2) + (lane >> 4) * 4;
  const int cbase = wc * 64 + (lane & 15);
  __syncthreads();
#pragma unroll
  for (int mg = 0; mg < BM / 32; mg++)
#pragma unroll
    for (int n = 0; n < 4; n++)
#pragma unroll
      for (int r = 0; r < 4; r++)
        sm[(rbase + mg * 16 + r) * BN + cbase + n * 16] = (f16)acc[mg][n][r];
  __syncthreads();
  constexpr int CH = BM * BN / (512 * 8);
#pragma unroll
  for (int c = 0; c < CH; c++) {
    const int idx = c * 512 + tid;
    const int row = idx / (BN / 8);
    const int cole = (idx % (BN / 8)) * 8;
    f16x8 v = *reinterpret_cast<const f16x8*>(&sm[row * BN + cole]);
    *reinterpret_cast<f16x8*>(Cp + (size_t)(m0 + row) * ldc + n0 + cole) = v;
  }
}

// ---------- epilogue: exp()->f16 store + per-coltile row sums ----------
template <int BM, int BN>
__device__ __forceinline__ void epi_exp(
    f32x4 (&acc)[BM / 32][4], f16* sm, float* psum, f16* Cp, int ldc,
    int m0, int n0, float scale, float* PSrow) {
  constexpr int SL = BN / 8;             // 16B slots per row
  const int tid = threadIdx.x, lane = tid & 63, wid = tid >> 6;
  const int wr = wid >> 2, wc = wid & 3;
  const int rbase = wr * (BM / 2) + (lane >> 4) * 4;
  const int cbase = wc * 64 + (lane & 15);
  __syncthreads();
#pragma unroll
  for (int mg = 0; mg < BM / 32; mg++)
#pragma unroll
    for (int n = 0; n < 4; n++)
#pragma unroll
      for (int r = 0; r < 4; r++)
        sm[(rbase + mg * 16 + r) * BN + cbase + n * 16] =
            (f16)__expf(acc[mg][n][r] * scale);
  __syncthreads();
  constexpr int CH = BM * BN / (512 * 8);
#pragma unroll
  for (int c = 0; c < CH; c++) {
    const int idx = c * 512 + tid;
    const int row = idx / SL;
    const int cole = (idx % SL) * 8;
    f16x8 v = *reinterpret_cast<const f16x8*>(&sm[row * BN + cole]);
    *reinterpret_cast<f16x8*>(Cp + (size_t)(m0 + row) * ldc + n0 + cole) = v;
    float p = 0.f;
#pragma unroll
    for (int j = 0; j < 8; j++) p += (float)v[j];
#pragma unroll
    for (int o = 1; o < SL; o <<= 1) p += __shfl_xor(p, o);
    if ((lane & (SL - 1)) == 0) psum[row] = p;   // one writer per row
  }
  __syncthreads();
  if (tid < BM) PSrow[tid] = psum[tid];
}

// ---------- epilogue: f32 store, LDS-staged (two half-passes) ----------
template <int BM, int BN>
__device__ __forceinline__ void epi_f32(
    f32x4 (&acc)[BM / 32][4], f16* smh, float* Cp, int ldc, int m0, int n0) {
  float* st = (float*)smh;               // (BM/2) x BN f32 per half-pass
  const int tid = threadIdx.x, lane = tid & 63, wid = tid >> 6;
  const int wr = wid >> 2, wc = wid & 3;
  const int cbase = wc * 64 + (lane & 15);
#pragma unroll
  for (int half = 0; half < 2; half++) {
    __syncthreads();
    if (wr == half) {
#pragma unroll
      for (int mg = 0; mg < BM / 32; mg++)
#pragma unroll
        for (int r = 0; r < 4; r++) {
          const int rloc = (lane >> 4) * 4 + mg * 16 + r;
#pragma unroll
          for (int n = 0; n < 4; n++)
            st[rloc * BN + cbase + n * 16] = acc[mg][n][r];
        }
    }
    __syncthreads();
    constexpr int CH = (BM / 2) * BN / (512 * 4);
#pragma unroll
    for (int c = 0; c < CH; c++) {
      const int idx = c * 512 + tid;
      const int row = idx / (BN / 4);
      const int cole = (idx % (BN / 4)) * 4;
      f32x4 v = *reinterpret_cast<const f32x4*>(&st[row * BN + cole]);
      *reinterpret_cast<f32x4*>(
          Cp + (size_t)(m0 + half * (BM / 2) + row) * ldc + n0 + cole) = v;
    }
  }
}

// ---------- fused input GEMM (128x256): blocks 0-255 q@WqT, 256-767 k@WkvT ----------
__global__ __launch_bounds__(512) void gemmIn_kernel(
    const f16* __restrict__ q16, const f16* __restrict__ WqT, f16* __restrict__ tmpq,
    const f16* __restrict__ k16, const f16* __restrict__ WkvT, f16* __restrict__ tmp2) {
  __shared__ __attribute__((aligned(16))) f16 sm[2 * (128 + 256) * 64];  // 96KB
  const int b = blockIdx.x;                       // 768
  const int swz = (b & 7) * 96 + (b >> 3);        // bijective XCD swizzle
  const f16 *A, *B;
  f16* C;
  int ldc, m0, n0;
  if (swz < 256) {                                // q: 64 m-tiles x 4 n-tiles
    const int bx = swz & 63, by = swz >> 6;
    A = q16; B = WqT; C = tmpq; ldc = 1024; m0 = bx * 128; n0 = by * 256;
  } else {                                        // kv: 64 m-tiles x 8 n-tiles
    const int idx = swz - 256;
    const int bx = idx & 63, by = idx >> 6;
    A = k16; B = WkvT; C = tmp2; ldc = 2048; m0 = bx * 128; n0 = by * 256;
  }
  f32x4 acc[4][4] = {};
  gemm_core2<128, 256>(A, B, 1024, 1024, 1024, m0, n0, sm, acc);
  epi_f16<128, 256>(acc, sm, C, ldc, m0, n0);
}

// ---------- s1 GEMM (256x256): e1 = exp(qn.kn^T/32), 8 col-tile partials ----------
__global__ __launch_bounds__(512) void gemmS1_kernel(
    const f16* __restrict__ qn, const f16* __restrict__ kn,
    f16* __restrict__ e1, float* __restrict__ PS) {
  __shared__ __attribute__((aligned(16))) f16 sm[2 * (256 + 256) * 64];  // 128KB
  __shared__ float psum[256];
  const int b = blockIdx.x;                       // 256
  const int swz = (b & 7) * 32 + (b >> 3);
  const int bz = swz >> 6;
  const int rem = swz & 63;
  const int bx = rem & 7, by = rem >> 3;          // 8 m x 8 n per batch
  const int m0 = bx * 256, n0 = by * 256;
  const f16* Ab = qn + (size_t)bz * 2048 * 1024;
  const f16* Bb = kn + (size_t)bz * 2048 * 2048;
  f16* Cp = e1 + (size_t)bz * 2048 * 2048;
  f32x4 acc[8][4] = {};
  gemm_core2<256, 256>(Ab, Bb, 1024, 2048, 1024, m0, n0, sm, acc);
  epi_exp<256, 256>(acc, sm, psum, Cp, 2048, m0, n0, 0.03125f,
                    PS + (size_t)by * (CB * CNQ) + bz * 2048 + m0);
}

// ---------- out GEMM (128x256): out = e2n @ vn ----------
__global__ __launch_bounds__(512) void gemmOut_kernel(
    const f16* __restrict__ e2, const f16* __restrict__ vnT, float* __restrict__ out) {
  __shared__ __attribute__((aligned(16))) f16 sm[2 * (128 + 256) * 64];  // 96KB
  const int b = blockIdx.x;                       // 256
  const int swz = (b & 7) * 32 + (b >> 3);
  const int bz = swz >> 6;
  const int rem = swz & 63;
  const int bx = rem & 15, by = rem >> 4;         // 16 m x 4 n per batch
  const int m0 = bx * 128, n0 = by * 256;
  const f16* Ab = e2 + (size_t)bz * 2048 * 2048;
  const f16* Bb = vnT + (size_t)bz * 1024 * 2048;
  float* Cp = out + (size_t)bz * 2048 * 1024;
  f32x4 acc[4][4] = {};
  gemm_core2<128, 256>(Ab, Bb, 2048, 2048, 2048, m0, n0, sm, acc);
  epi_f32<128, 256>(acc, sm, Cp, 1024, m0, n0);
}

// ---------- merged LayerNorm: z=0 q in place, z=1 k in place, z=2 v STATS only ----------
__global__ __launch_bounds__(256) void ln3_kernel(
    f16* __restrict__ tmpq, f16* __restrict__ tmp2, float* __restrict__ vstat,
    const float* __restrict__ bq, const float* __restrict__ gq, const float* __restrict__ beq,
    const float* __restrict__ bk, const float* __restrict__ gk, const float* __restrict__ bek,
    const float* __restrict__ bv) {
  __shared__ float rs_[4], rq_[4];
  const int z = blockIdx.y;
  f16* rp;
  const float *bias, *g, *beta;
  if (z == 0)      { rp = tmpq + (size_t)blockIdx.x * 1024;        bias = bq; g = gq; beta = beq; }
  else if (z == 1) { rp = tmp2 + (size_t)blockIdx.x * 2048;        bias = bk; g = gk; beta = bek; }
  else             { rp = tmp2 + (size_t)blockIdx.x * 2048 + 1024; bias = bv; g = nullptr; beta = nullptr; }
  const int t = threadIdx.x;
  f16x4 v = *reinterpret_cast<const f16x4*>(rp + t * 4);
  float y[4], s = 0.f, q = 0.f;
#pragma unroll
  for (int j = 0; j < 4; j++) {
    y[j] = (float)v[j] + bias[t * 4 + j];
    s += y[j]; q += y[j] * y[j];
  }
#pragma unroll
  for (int o = 32; o; o >>= 1) { s += __shfl_xor(s, o); q += __shfl_xor(q, o); }
  if ((t & 63) == 0) { rs_[t >> 6] = s; rq_[t >> 6] = q; }
  __syncthreads();
  s = rs_[0] + rs_[1] + rs_[2] + rs_[3];
  q = rq_[0] + rq_[1] + rq_[2] + rq_[3];
  const float mean = s * (1.0f / CD);
  const float rstd = rsqrtf(q * (1.0f / CD) - mean * mean + 1e-5f);
  if (z == 2) {                          // stats only; transpose applies LN
    if (t == 0) { vstat[blockIdx.x] = mean; vstat[CB * CNK + blockIdx.x] = rstd; }
    return;
  }
  f16x4 o;
#pragma unroll
  for (int j = 0; j < 4; j++) {
    int c = t * 4 + j;
    o[j] = (f16)((y[j] - mean) * rstd * g[c] + beta[c]);
  }
  *reinterpret_cast<f16x4*>(rp + t * 4) = o;
}

// ---------- transpose + apply v-LN: vnT[b][d][n] = LN(tmp2v[b][n][d]) ----------
__global__ __launch_bounds__(256) void transposeLN_kernel(
    const f16* __restrict__ tmp2, f16* __restrict__ vnT,
    const float* __restrict__ vstat, const float* __restrict__ bv,
    const float* __restrict__ gv, const float* __restrict__ bev) {
  __shared__ f16 t[64][65];
  __shared__ float ms[64], rs[64];
  int n0 = blockIdx.x * 64, d0 = blockIdx.y * 64;
  size_t ibase = (size_t)blockIdx.z * CNK * 2048;
  size_t obase = (size_t)blockIdx.z * CNK * CD;
  int tx = threadIdx.x & 63, ty = threadIdx.x >> 6;
  const int tokbase = blockIdx.z * CNK + n0;
  if (threadIdx.x < 64) {
    ms[threadIdx.x] = vstat[tokbase + threadIdx.x];
    rs[threadIdx.x] = vstat[CB * CNK + tokbase + threadIdx.x];
  }
#pragma unroll
  for (int i = 0; i < 16; i++)
    t[ty + 4 * i][tx] = tmp2[ibase + (size_t)(n0 + ty + 4 * i) * 2048 + 1024 + d0 + tx];
  __syncthreads();
#pragma unroll
  for (int i = 0; i < 16; i++) {
    const int dim = d0 + 4 * i + ty;
    const float yv = (float)t[tx][ty + 4 * i] + bv[dim];
    vnT[obase + (size_t)dim * CNK + n0 + tx] =
        (f16)((yv - ms[tx]) * rs[tx] * gv[dim] + bev[dim]);
  }
}

// ---------- attn2 (16 rows/block, 2 blocks/CU): absorbs x = e1@pos (K-split
// across 8 waves + LDS reduce) and the att0 = e1*inv1 write; then
// x'=x@Wp+bp; e=exp(x'.pos^T/8); writes normalized att head-1 + e2 ----------
__global__ __launch_bounds__(512) void attn2_kernel(
    const f16* __restrict__ e1, const f16* __restrict__ posTb,
    const float* __restrict__ Wp, const float* __restrict__ bp,
    const f16* __restrict__ posb, const float* __restrict__ PS,
    f16* __restrict__ e2, float* __restrict__ att) {
  // shm regions (f16 view, 67.8KB):
  //   [0 .. 16*ELD)        e2lds (phase 4+)   -- aliased in phases 1-3 by:
  //       part  f32[8][16][64]  at +0     (32KB)
  //       xs    f32[16][64]     at +32KB  (4KB)
  //       Wps   f32[64][64]     at +36KB  (16KB)
  //   [16*ELD ..)          xpb f16[16][64]
  constexpr int ELD = 2056;
  __shared__ __attribute__((aligned(16))) f16 shm[16 * ELD + 16 * 64];
  __shared__ float rsum8[8][16];
  __shared__ float invs[16];
  f16* e2lds = shm;
  f16* xpb = shm + 16 * ELD;
  float* part = (float*)shm;            // [8][1024]
  float* xs   = (float*)shm + 8 * 1024; // [16][64]
  float* Wps  = (float*)shm + 9 * 1024; // [64][64]
  const int tid = threadIdx.x, l = tid & 63, w = tid >> 6;   // w 0..7
  const int r0 = blockIdx.x * 16;
  if (tid < 16) {
    float s = 0.f;
#pragma unroll
    for (int j = 0; j < 8; j++) s += PS[j * (CB * CNQ) + r0 + tid];
    invs[tid] = 1.0f / s;
  }
  __syncthreads();

  // ---- phase 1: partial x (wave w covers K range [w*256, w*256+256))
  //      + att0 write from the same e1 fragments ----
  const int row16 = l & 15, kg8 = (l >> 4) * 8;
  const int bb = r0 >> 11, nloc = r0 & (CNQ - 1);
  float* att0b = att + ((size_t)(bb << 1) * CNQ + nloc) * CNK;
  const float ivr = invs[row16];
  f32x4 xacc[4] = {};
#pragma unroll
  for (int i = 0; i < 8; i++) {
    const int kcol = w * 256 + i * 32 + kg8;
    f16x8 af = *reinterpret_cast<const f16x8*>(
        &e1[(size_t)(r0 + row16) * CNK + kcol]);
    // att0 = e1 * inv1 (this lane's 8 cols of its row)
    f32x4 w0 = {(float)af[0] * ivr, (float)af[1] * ivr,
                (float)af[2] * ivr, (float)af[3] * ivr};
    f32x4 w1 = {(float)af[4] * ivr, (float)af[5] * ivr,
                (float)af[6] * ivr, (float)af[7] * ivr};
    float* ap = att0b + (size_t)row16 * CNK + kcol;
    *reinterpret_cast<f32x4*>(ap)     = w0;
    *reinterpret_cast<f32x4*>(ap + 4) = w1;
#pragma unroll
    for (int nf = 0; nf < 4; nf++) {
      f16x8 bf = *reinterpret_cast<const f16x8*>(
          &posTb[(size_t)(nf * 16 + row16) * CNK + kcol]);
      xacc[nf] = __builtin_amdgcn_mfma_f32_16x16x32_f16(af, bf, xacc[nf], 0, 0, 0);
    }
  }
  // store partials: C-layout row = (l>>4)*4+r, col = nf*16 + (l&15)
#pragma unroll
  for (int nf = 0; nf < 4; nf++)
#pragma unroll
    for (int r = 0; r < 4; r++)
      part[w * 1024 + ((l >> 4) * 4 + r) * 64 + nf * 16 + (l & 15)] = xacc[nf][r];
  __syncthreads();

  // ---- phase 2: reduce partials -> xs (inv1 already applied); load Wps ----
#pragma unroll
  for (int idx = tid; idx < 1024; idx += 512) {
    float s = 0.f;
#pragma unroll
    for (int h = 0; h < 8; h++) s += part[h * 1024 + idx];
    xs[idx] = s * invs[idx >> 6];
  }
#pragma unroll
  for (int idx = tid; idx < 4096; idx += 512) Wps[idx] = Wp[idx];
  const float bpl = bp[l];
  __syncthreads();

  // ---- phase 3: x' = xs @ Wps + bp (waves 0-1, 8 rows each) ----
  if (w < 2) {
#pragma unroll 2
    for (int i = 0; i < 8; i++) {
      const int row = w * 8 + i;
      float a = bpl;
#pragma unroll 8
      for (int p = 0; p < 64; p++) a = fmaf(xs[row * 64 + p], Wps[p * 64 + l], a);
      xpb[row * 64 + l] = (f16)a;
    }
  }
  __syncthreads();                       // xpb ready; part/xs/Wps dead -> e2lds free

  // ---- phase 4: e2 = exp(x'.pos^T/8), 8-way j-split ----
  const f16x8 af0 = *reinterpret_cast<const f16x8*>(&xpb[(l & 15) * 64 + (l >> 4) * 8]);
  const f16x8 af1 = *reinterpret_cast<const f16x8*>(&xpb[(l & 15) * 64 + 32 + (l >> 4) * 8]);
  float rs[4] = {0.f, 0.f, 0.f, 0.f};
  for (int jt = w * 4; jt < w * 4 + 4; jt++) {
#pragma unroll
    for (int q4 = 0; q4 < 4; q4++) {
      const int j = jt * 64 + q4 * 16 + (l & 15);
      const f16* pp = posb + (size_t)j * CP + (l >> 4) * 8;
      f16x8 b0 = *reinterpret_cast<const f16x8*>(pp);
      f16x8 b1 = *reinterpret_cast<const f16x8*>(pp + 32);
      f32x4 c = {};
      c = __builtin_amdgcn_mfma_f32_16x16x32_f16(af0, b0, c, 0, 0, 0);
      c = __builtin_amdgcn_mfma_f32_16x16x32_f16(af1, b1, c, 0, 0, 0);
#pragma unroll
      for (int r = 0; r < 4; r++) {
        float ev = __expf(c[r] * 0.125f);
        rs[r] += ev;
        e2lds[((l >> 4) * 4 + r) * ELD + j] = (f16)ev;
      }
    }
  }
#pragma unroll
  for (int r = 0; r < 4; r++) {
#pragma unroll
    for (int o = 1; o < 16; o <<= 1) rs[r] += __shfl_xor(rs[r], o);
    if ((l & 15) == 0) rsum8[w][(l >> 4) * 4 + r] = rs[r];
  }
  __syncthreads();

  // ---- phase 5: normalized att head-1 (f32) + e2 (f16) ----
  float* att1b = att + ((size_t)((bb << 1) + 1) * CNQ + nloc) * CNK;
  f16* e2b = e2 + (size_t)r0 * CNK;
  for (int it = 0; it < 4; it++) {
    const int row = it * 4 + (tid >> 7);
    const int col = (tid & 127) * 16;
    float s = 0.f;
#pragma unroll
    for (int h = 0; h < 8; h++) s += rsum8[h][row];
    const float iv = 1.0f / s;
    const f16x8 a0 = *reinterpret_cast<const f16x8*>(&e2lds[row * ELD + col]);
    const f16x8 a1 = *reinterpret_cast<const f16x8*>(&e2lds[row * ELD + col + 8]);
    f32x4 w0 = {(float)a0[0] * iv, (float)a0[1] * iv, (float)a0[2] * iv, (float)a0[3] * iv};
    f32x4 w1 = {(float)a0[4] * iv, (float)a0[5] * iv, (float)a0[6] * iv, (float)a0[7] * iv};
    f32x4 w2 = {(float)a1[0] * iv, (float)a1[1] * iv, (float)a1[2] * iv, (float)a1[3] * iv};
    f32x4 w3 = {(float)a1[4] * iv, (float)a1[5] * iv, (float)a1[6] * iv, (float)a1[7] * iv};
    float* ap = att1b + (size_t)row * CNK + col;
    *reinterpret_cast<f32x4*>(ap)      = w0;
    *reinterpret_cast<f32x4*>(ap + 4)  = w1;
    *reinterpret_cast<f32x4*>(ap + 8)  = w2;
    *reinterpret_cast<f32x4*>(ap + 12) = w3;
    f16x8 h0 = {(f16)w0[0], (f16)w0[1], (f16)w0[2], (f16)w0[3],
                (f16)w1[0], (f16)w1[1], (f16)w1[2], (f16)w1[3]};
    f16x8 h1 = {(f16)w2[0], (f16)w2[1], (f16)w2[2], (f16)w2[3],
                (f16)w3[0], (f16)w3[1], (f16)w3[2], (f16)w3[3]};
    f16* ep = e2b + (size_t)row * CNK + col;
    *reinterpret_cast<f16x8*>(ep)     = h0;
    *reinterpret_cast<f16x8*>(ep + 8) = h1;
  }
}

extern "C" void kernel_launch(void* const* d_in, const int* in_sizes, int n_in,
                              void* d_out, int out_size, void* d_ws, size_t ws_size,
                              hipStream_t stream) {
  (void)in_sizes; (void)n_in; (void)out_size; (void)ws_size;
  const float* q    = (const float*)d_in[0];
  const float* k    = (const float*)d_in[1];
  const float* Wq   = (const float*)d_in[2];
  const float* bq   = (const float*)d_in[3];
  const float* Wk   = (const float*)d_in[4];
  const float* bk   = (const float*)d_in[5];
  const float* Wv   = (const float*)d_in[6];
  const float* bv   = (const float*)d_in[7];
  const float* gq   = (const float*)d_in[8];
  const float* betaq= (const float*)d_in[9];
  const float* gk   = (const float*)d_in[10];
  const float* betak= (const float*)d_in[11];
  const float* gv   = (const float*)d_in[12];
  const float* betav= (const float*)d_in[13];
  const float* Wp   = (const float*)d_in[14];
  const float* bp   = (const float*)d_in[15];

  float* out = (float*)d_out;
  float* att = out + (size_t)CB * CNQ * CD;   // [B,2,NQ,NK]
  char* ws = (char*)d_ws;
  const size_t MB = 1ull << 20;

  f16* q16   = (f16*)(ws);                     // 0-16MB, dead after gemmIn
  f16* k16   = (f16*)(ws + 16 * MB);           // 16-32, dead after gemmIn
  f16* e1    = (f16*)(ws);                     // 0-32 (after q16/k16 die)
  f16* e2    = (f16*)(ws);                     // 0-32 (after e1 dies)
  f16* WqT   = (f16*)(ws + 32 * MB);           // 2MB
  f16* WkvT  = (f16*)(ws + 34 * MB);           // 4MB
  f16* posb  = (f16*)(ws + 38 * MB);           // 256KB
  f16* posTb = (f16*)(ws + 38 * MB + 256 * 1024);
  float* PS  = (float*)(ws + 42 * MB + 512 * 1024); // 256KB [8][8192]
  float* vstat = (float*)(ws + 42 * MB + 768 * 1024); // 64KB [2][8192]
  f16* tmpq  = (f16*)(ws + 43 * MB);           // 16MB (qn in place)
  f16* tmp2  = (f16*)(ws + 59 * MB);           // 32MB (kn in place | v raw)
  f16* vnT   = (f16*)(ws + 91 * MB);           // 16MB (ends 107MB)
  f16* qn = tmpq;
  f16* kn = tmp2;            // ld 2048, cols 0-1023

  prep_kernel<<<512 + 16384 + 768, 256, 0, stream>>>(
      q, k, Wq, Wk, Wv, q16, k16, WqT, WkvT, posb, posTb);

  gemmIn_kernel<<<768, 512, 0, stream>>>(q16, WqT, tmpq, k16, WkvT, tmp2);
  ln3_kernel<<<dim3(CB * CNQ, 3), 256, 0, stream>>>(
      tmpq, tmp2, vstat, bq, gq, betaq, bk, gk, betak, bv);
  transposeLN_kernel<<<dim3(CNK / 64, CD / 64, CB), 256, 0, stream>>>(
      tmp2, vnT, vstat, bv, gv, betav);

  gemmS1_kernel<<<256, 512, 0, stream>>>(qn, kn, e1, PS);

  attn2_kernel<<<CB * CNQ / 16, 512, 0, stream>>>(
      e1, posTb, Wp, bp, posb, PS, e2, att);

  gemmOut_kernel<<<256, 512, 0, stream>>>(e2, vnT, out);
}

// Round 16
// 281.021 us; speedup vs baseline: 1.0107x; 1.0107x over previous
//
#include <hip/hip_runtime.h>
#include <math.h>
#include <stdint.h>

// BlindCrossAttention on MI355X (gfx950).
// Round 16 = exact revert to Round 14 (best measured: 281.4 us).
// r15's xgemm-into-attn2 fusion was slightly negative; restored.

typedef _Float16 f16;
typedef _Float16 f16x4 __attribute__((ext_vector_type(4)));
typedef _Float16 f16x8 __attribute__((ext_vector_type(8)));
typedef float f32x4 __attribute__((ext_vector_type(4)));

static constexpr int CB  = 4;
static constexpr int CNQ = 2048;
static constexpr int CNK = 2048;
static constexpr int CD  = 1024;
static constexpr int CP  = 64;

// ---------- async global->LDS, 16B/lane ----------
static __device__ __forceinline__ void async16(const f16* gp, f16* lp) {
  __builtin_amdgcn_global_load_lds(
      (const __attribute__((address_space(1))) void*)(uintptr_t)gp,
      (__attribute__((address_space(3))) void*)(uint32_t)(uintptr_t)lp,
      16, 0, 0);
}

// ---------- prep: pos table + cvt q,k -> f16 + transpose-cvt W's ----------
__global__ __launch_bounds__(256) void prep_kernel(
    const float* __restrict__ q, const float* __restrict__ k,
    const float* __restrict__ Wq, const float* __restrict__ Wk,
    const float* __restrict__ Wv,
    f16* __restrict__ q16, f16* __restrict__ k16,
    f16* __restrict__ WqT, f16* __restrict__ WkvT,
    f16* __restrict__ posb, f16* __restrict__ posTb) {
  const int b = blockIdx.x;
  if (b < 512) {                        // pos table
    int tid = b * 256 + threadIdx.x;
    int p = tid >> 11;
    int j = tid & (CNK - 1);
    int i = p & 31;
    float ph = (float)j * powf(10000.0f, -(float)i * (1.0f / 32.0f));
    float v = (p < 32) ? sinf(ph) : cosf(ph);
    posb[j * CP + p]   = (f16)v;
    posTb[p * CNK + j] = (f16)v;
  } else if (b < 512 + 16384) {         // cvt q,k
    const int NF4 = CB * CNQ * CD / 4;
    int tid = (b - 512) * 256 + threadIdx.x;
    const float* src = (tid < NF4) ? q : k;
    f16* dst = (tid < NF4) ? q16 : k16;
    int i = (tid < NF4) ? tid : tid - NF4;
    float4 v = reinterpret_cast<const float4*>(src)[i];
    f16x4 o = {(f16)v.x, (f16)v.y, (f16)v.z, (f16)v.w};
    reinterpret_cast<f16x4*>(dst)[i] = o;
  } else {                              // W -> WT f16
    __shared__ float t[64][65];
    const int idx = b - 16896;
    const int z = idx >> 8;
    const int rem = idx & 255;
    const float* W = (z == 0) ? Wq : (z == 1) ? Wk : Wv;
    f16* WT = (z == 0) ? WqT : (z == 1) ? WkvT : WkvT + 1024 * 1024;
    int k0 = (rem & 15) * 64, n0 = (rem >> 4) * 64;
    int tx = threadIdx.x & 63, ty = threadIdx.x >> 6;
#pragma unroll
    for (int i = 0; i < 16; i++)
      t[ty + 4 * i][tx] = W[(size_t)(k0 + ty + 4 * i) * CD + n0 + tx];
    __syncthreads();
#pragma unroll
    for (int i = 0; i < 16; i++)
      WT[(size_t)(n0 + 4 * i + ty) * CD + k0 + tx] = (f16)t[tx][ty + 4 * i];
  }
}

// ============ 2-barrier counted-prefetch dbuf GEMM core (wide waves) ============
template <int BM, int BN>
__device__ __forceinline__ void gemm_core2(
    const f16* __restrict__ Ab, const f16* __restrict__ Bb,
    int lda, int ldb, int K, int m0, int n0, f16* sm,
    f32x4 (&acc)[BM / 32][4]) {
  constexpr int FM = BM / 32;           // 4 or 8
  constexpr int TI = (BM + BN) / 64;    // 6 or 8
  constexpr int bufsz = (BM + BN) * 64;
  const int tid = threadIdx.x;
  const int lane = tid & 63, wid = tid >> 6;
  const int wr = wid >> 2, wc = wid & 3;
  const int lrow = lane & 15, kg = lane >> 4;

  auto stage = [&](int i, int kt, int buf) {
    const int s = i * 512 + tid;          // 16B slot
    const int row = s >> 3;
    const int cb = (s & 7) << 4;
    const int scb = cb ^ ((row & 7) << 4);  // pre-swizzled global source col
    const f16* src = (i < BM / 64)
        ? Ab + (size_t)(m0 + row) * lda + kt * 64 + (scb >> 1)
        : Bb + (size_t)(n0 + row - BM) * ldb + kt * 64 + (scb >> 1);
    async16(src, &sm[buf * bufsz + s * 8]);
  };

  const int NTk = K >> 6;
#pragma unroll
  for (int i = 0; i < TI; i++) stage(i, 0, 0);

  for (int t = 0; t < NTk; ++t) {
    const int cur = t & 1;
    if (t + 1 < NTk) {
#pragma unroll
      for (int i = 0; i < TI; i++) stage(i, t + 1, cur ^ 1);
      if constexpr (TI == 8) asm volatile("s_waitcnt vmcnt(8)" ::: "memory");
      else                   asm volatile("s_waitcnt vmcnt(6)" ::: "memory");
    } else {
      asm volatile("s_waitcnt vmcnt(0)" ::: "memory");
    }
    __builtin_amdgcn_s_barrier();        // tile t data ready in buf[cur]

    const f16* smA = sm + cur * bufsz;
    const f16* smB = smA + BM * 64;
    __builtin_amdgcn_s_setprio(1);
#pragma unroll
    for (int kk = 0; kk < 2; ++kk) {
      const int Cb = kk * 64 + kg * 16;
      f16x8 af[FM], bf[4];
#pragma unroll
      for (int m = 0; m < FM; ++m) {
        const int ar = wr * (BM / 2) + m * 16 + lrow;
        af[m] = *reinterpret_cast<const f16x8*>(
            &smA[ar * 64 + ((Cb ^ ((ar & 7) << 4)) >> 1)]);
      }
#pragma unroll
      for (int n = 0; n < 4; ++n) {
        const int br = wc * 64 + n * 16 + lrow;
        bf[n] = *reinterpret_cast<const f16x8*>(
            &smB[br * 64 + ((Cb ^ ((br & 7) << 4)) >> 1)]);
      }
#pragma unroll
      for (int m = 0; m < FM; ++m)
#pragma unroll
        for (int n = 0; n < 4; ++n)
          acc[m][n] = __builtin_amdgcn_mfma_f32_16x16x32_f16(af[m], bf[n], acc[m][n], 0, 0, 0);
    }
    __builtin_amdgcn_s_setprio(0);
    __builtin_amdgcn_s_barrier();        // all reads of buf[cur] done
  }
}

// ---------- epilogue: f16 store, LDS-staged ----------
template <int BM, int BN>
__device__ __forceinline__ void epi_f16(
    f32x4 (&acc)[BM / 32][4], f16* sm, f16* Cp, int ldc, int m0, int n0) {
  const int tid = threadIdx.x, lane = tid & 63, wid = tid >> 6;
  const int wr = wid >> 2, wc = wid & 3;
  const int rbase = wr * (BM / 2) + (lane >> 4) * 4;
  const int cbase = wc * 64 + (lane & 15);
  __syncthreads();
#pragma unroll
  for (int mg = 0; mg < BM / 32; mg++)
#pragma unroll
    for (int n = 0; n < 4; n++)
#pragma unroll
      for (int r = 0; r < 4; r++)
        sm[(rbase + mg * 16 + r) * BN + cbase + n * 16] = (f16)acc[mg][n][r];
  __syncthreads();
  constexpr int CH = BM * BN / (512 * 8);
#pragma unroll
  for (int c = 0; c < CH; c++) {
    const int idx = c * 512 + tid;
    const int row = idx / (BN / 8);
    const int cole = (idx % (BN / 8)) * 8;
    f16x8 v = *reinterpret_cast<const f16x8*>(&sm[row * BN + cole]);
    *reinterpret_cast<f16x8*>(Cp + (size_t)(m0 + row) * ldc + n0 + cole) = v;
  }
}

// ---------- epilogue: exp()->f16 store + per-coltile row sums ----------
template <int BM, int BN>
__device__ __forceinline__ void epi_exp(
    f32x4 (&acc)[BM / 32][4], f16* sm, float* psum, f16* Cp, int ldc,
    int m0, int n0, float scale, float* PSrow) {
  constexpr int SL = BN / 8;             // 16B slots per row
  const int tid = threadIdx.x, lane = tid & 63, wid = tid >> 6;
  const int wr = wid >> 2, wc = wid & 3;
  const int rbase = wr * (BM / 2) + (lane >> 4) * 4;
  const int cbase = wc * 64 + (lane & 15);
  __syncthreads();
#pragma unroll
  for (int mg = 0; mg < BM / 32; mg++)
#pragma unroll
    for (int n = 0; n < 4; n++)
#pragma unroll
      for (int r = 0; r < 4; r++)
        sm[(rbase + mg * 16 + r) * BN + cbase + n * 16] =
            (f16)__expf(acc[mg][n][r] * scale);
  __syncthreads();
  constexpr int CH = BM * BN / (512 * 8);
#pragma unroll
  for (int c = 0; c < CH; c++) {
    const int idx = c * 512 + tid;
    const int row = idx / SL;
    const int cole = (idx % SL) * 8;
    f16x8 v = *reinterpret_cast<const f16x8*>(&sm[row * BN + cole]);
    *reinterpret_cast<f16x8*>(Cp + (size_t)(m0 + row) * ldc + n0 + cole) = v;
    float p = 0.f;
#pragma unroll
    for (int j = 0; j < 8; j++) p += (float)v[j];
#pragma unroll
    for (int o = 1; o < SL; o <<= 1) p += __shfl_xor(p, o);
    if ((lane & (SL - 1)) == 0) psum[row] = p;   // one writer per row
  }
  __syncthreads();
  if (tid < BM) PSrow[tid] = psum[tid];
}

// ---------- epilogue: f32 store, LDS-staged (two half-passes) ----------
template <int BM, int BN>
__device__ __forceinline__ void epi_f32(
    f32x4 (&acc)[BM / 32][4], f16* smh, float* Cp, int ldc, int m0, int n0) {
  float* st = (float*)smh;               // (BM/2) x BN f32 per half-pass
  const int tid = threadIdx.x, lane = tid & 63, wid = tid >> 6;
  const int wr = wid >> 2, wc = wid & 3;
  const int cbase = wc * 64 + (lane & 15);
#pragma unroll
  for (int half = 0; half < 2; half++) {
    __syncthreads();
    if (wr == half) {
#pragma unroll
      for (int mg = 0; mg < BM / 32; mg++)
#pragma unroll
        for (int r = 0; r < 4; r++) {
          const int rloc = (lane >> 4) * 4 + mg * 16 + r;
#pragma unroll
          for (int n = 0; n < 4; n++)
            st[rloc * BN + cbase + n * 16] = acc[mg][n][r];
        }
    }
    __syncthreads();
    constexpr int CH = (BM / 2) * BN / (512 * 4);
#pragma unroll
    for (int c = 0; c < CH; c++) {
      const int idx = c * 512 + tid;
      const int row = idx / (BN / 4);
      const int cole = (idx % (BN / 4)) * 4;
      f32x4 v = *reinterpret_cast<const f32x4*>(&st[row * BN + cole]);
      *reinterpret_cast<f32x4*>(
          Cp + (size_t)(m0 + half * (BM / 2) + row) * ldc + n0 + cole) = v;
    }
  }
}

// ---------- fused input GEMM (128x256): blocks 0-255 q@WqT, 256-767 k@WkvT ----------
__global__ __launch_bounds__(512) void gemmIn_kernel(
    const f16* __restrict__ q16, const f16* __restrict__ WqT, f16* __restrict__ tmpq,
    const f16* __restrict__ k16, const f16* __restrict__ WkvT, f16* __restrict__ tmp2) {
  __shared__ __attribute__((aligned(16))) f16 sm[2 * (128 + 256) * 64];  // 96KB
  const int b = blockIdx.x;                       // 768
  const int swz = (b & 7) * 96 + (b >> 3);        // bijective XCD swizzle
  const f16 *A, *B;
  f16* C;
  int ldc, m0, n0;
  if (swz < 256) {                                // q: 64 m-tiles x 4 n-tiles
    const int bx = swz & 63, by = swz >> 6;
    A = q16; B = WqT; C = tmpq; ldc = 1024; m0 = bx * 128; n0 = by * 256;
  } else {                                        // kv: 64 m-tiles x 8 n-tiles
    const int idx = swz - 256;
    const int bx = idx & 63, by = idx >> 6;
    A = k16; B = WkvT; C = tmp2; ldc = 2048; m0 = bx * 128; n0 = by * 256;
  }
  f32x4 acc[4][4] = {};
  gemm_core2<128, 256>(A, B, 1024, 1024, 1024, m0, n0, sm, acc);
  epi_f16<128, 256>(acc, sm, C, ldc, m0, n0);
}

// ---------- s1 GEMM (256x256): e1 = exp(qn.kn^T/32), 8 col-tile partials ----------
__global__ __launch_bounds__(512) void gemmS1_kernel(
    const f16* __restrict__ qn, const f16* __restrict__ kn,
    f16* __restrict__ e1, float* __restrict__ PS) {
  __shared__ __attribute__((aligned(16))) f16 sm[2 * (256 + 256) * 64];  // 128KB
  __shared__ float psum[256];
  const int b = blockIdx.x;                       // 256
  const int swz = (b & 7) * 32 + (b >> 3);
  const int bz = swz >> 6;
  const int rem = swz & 63;
  const int bx = rem & 7, by = rem >> 3;          // 8 m x 8 n per batch
  const int m0 = bx * 256, n0 = by * 256;
  const f16* Ab = qn + (size_t)bz * 2048 * 1024;
  const f16* Bb = kn + (size_t)bz * 2048 * 2048;
  f16* Cp = e1 + (size_t)bz * 2048 * 2048;
  f32x4 acc[8][4] = {};
  gemm_core2<256, 256>(Ab, Bb, 1024, 2048, 1024, m0, n0, sm, acc);
  epi_exp<256, 256>(acc, sm, psum, Cp, 2048, m0, n0, 0.03125f,
                    PS + (size_t)by * (CB * CNQ) + bz * 2048 + m0);
}

// ---------- out GEMM (128x256): out = e2n @ vn ----------
__global__ __launch_bounds__(512) void gemmOut_kernel(
    const f16* __restrict__ e2, const f16* __restrict__ vnT, float* __restrict__ out) {
  __shared__ __attribute__((aligned(16))) f16 sm[2 * (128 + 256) * 64];  // 96KB
  const int b = blockIdx.x;                       // 256
  const int swz = (b & 7) * 32 + (b >> 3);
  const int bz = swz >> 6;
  const int rem = swz & 63;
  const int bx = rem & 15, by = rem >> 4;         // 16 m x 4 n per batch
  const int m0 = bx * 128, n0 = by * 256;
  const f16* Ab = e2 + (size_t)bz * 2048 * 2048;
  const f16* Bb = vnT + (size_t)bz * 1024 * 2048;
  float* Cp = out + (size_t)bz * 2048 * 1024;
  f32x4 acc[4][4] = {};
  gemm_core2<128, 256>(Ab, Bb, 2048, 2048, 2048, m0, n0, sm, acc);
  epi_f32<128, 256>(acc, sm, Cp, 1024, m0, n0);
}

// ---------- merged LayerNorm: z=0 q in place, z=1 k in place, z=2 v STATS only ----------
__global__ __launch_bounds__(256) void ln3_kernel(
    f16* __restrict__ tmpq, f16* __restrict__ tmp2, float* __restrict__ vstat,
    const float* __restrict__ bq, const float* __restrict__ gq, const float* __restrict__ beq,
    const float* __restrict__ bk, const float* __restrict__ gk, const float* __restrict__ bek,
    const float* __restrict__ bv) {
  __shared__ float rs_[4], rq_[4];
  const int z = blockIdx.y;
  f16* rp;
  const float *bias, *g, *beta;
  if (z == 0)      { rp = tmpq + (size_t)blockIdx.x * 1024;        bias = bq; g = gq; beta = beq; }
  else if (z == 1) { rp = tmp2 + (size_t)blockIdx.x * 2048;        bias = bk; g = gk; beta = bek; }
  else             { rp = tmp2 + (size_t)blockIdx.x * 2048 + 1024; bias = bv; g = nullptr; beta = nullptr; }
  const int t = threadIdx.x;
  f16x4 v = *reinterpret_cast<const f16x4*>(rp + t * 4);
  float y[4], s = 0.f, q = 0.f;
#pragma unroll
  for (int j = 0; j < 4; j++) {
    y[j] = (float)v[j] + bias[t * 4 + j];
    s += y[j]; q += y[j] * y[j];
  }
#pragma unroll
  for (int o = 32; o; o >>= 1) { s += __shfl_xor(s, o); q += __shfl_xor(q, o); }
  if ((t & 63) == 0) { rs_[t >> 6] = s; rq_[t >> 6] = q; }
  __syncthreads();
  s = rs_[0] + rs_[1] + rs_[2] + rs_[3];
  q = rq_[0] + rq_[1] + rq_[2] + rq_[3];
  const float mean = s * (1.0f / CD);
  const float rstd = rsqrtf(q * (1.0f / CD) - mean * mean + 1e-5f);
  if (z == 2) {                          // stats only; transpose applies LN
    if (t == 0) { vstat[blockIdx.x] = mean; vstat[CB * CNK + blockIdx.x] = rstd; }
    return;
  }
  f16x4 o;
#pragma unroll
  for (int j = 0; j < 4; j++) {
    int c = t * 4 + j;
    o[j] = (f16)((y[j] - mean) * rstd * g[c] + beta[c]);
  }
  *reinterpret_cast<f16x4*>(rp + t * 4) = o;
}

// ---------- transpose + apply v-LN: vnT[b][d][n] = LN(tmp2v[b][n][d]) ----------
__global__ __launch_bounds__(256) void transposeLN_kernel(
    const f16* __restrict__ tmp2, f16* __restrict__ vnT,
    const float* __restrict__ vstat, const float* __restrict__ bv,
    const float* __restrict__ gv, const float* __restrict__ bev) {
  __shared__ f16 t[64][65];
  __shared__ float ms[64], rs[64];
  int n0 = blockIdx.x * 64, d0 = blockIdx.y * 64;
  size_t ibase = (size_t)blockIdx.z * CNK * 2048;
  size_t obase = (size_t)blockIdx.z * CNK * CD;
  int tx = threadIdx.x & 63, ty = threadIdx.x >> 6;
  const int tokbase = blockIdx.z * CNK + n0;
  if (threadIdx.x < 64) {
    ms[threadIdx.x] = vstat[tokbase + threadIdx.x];
    rs[threadIdx.x] = vstat[CB * CNK + tokbase + threadIdx.x];
  }
#pragma unroll
  for (int i = 0; i < 16; i++)
    t[ty + 4 * i][tx] = tmp2[ibase + (size_t)(n0 + ty + 4 * i) * 2048 + 1024 + d0 + tx];
  __syncthreads();
#pragma unroll
  for (int i = 0; i < 16; i++) {
    const int dim = d0 + 4 * i + ty;
    const float yv = (float)t[tx][ty + 4 * i] + bv[dim];
    vnT[obase + (size_t)dim * CNK + n0 + tx] =
        (f16)((yv - ms[tx]) * rs[tx] * gv[dim] + bev[dim]);
  }
}

// ---------- x-GEMM v3: xw[z] = e1 @ pos (K half z), 8-wave dbuf counted core;
//            att0 = e1*inv1 written IN-LOOP from the staged LDS tile ----------
__global__ __launch_bounds__(512) void xgemm_kernel(
    const f16* __restrict__ e1, const f16* __restrict__ posTb,
    const float* __restrict__ PS, float* __restrict__ xw, float* __restrict__ att) {
  // LDS: 2 buf x (64 A-rows + 64 B-rows) x 64 f16 = 32 KB
  __shared__ __attribute__((aligned(16))) f16 sm[2 * 128 * 64];
  __shared__ float invs[64];
  const int tid = threadIdx.x, lane = tid & 63, wid = tid >> 6;  // 8 waves
  const int wr = wid >> 1, wc = wid & 1;       // wave tile 16x32
  const int lrow = lane & 15, kg = lane >> 4;
  const int m0 = blockIdx.x * 64;
  const int kbase = blockIdx.z * 1024;

  if (tid < 64) {                  // inv1 from the 8 PS partials
    float s = 0.f;
#pragma unroll
    for (int j = 0; j < 8; j++) s += PS[j * (CB * CNQ) + m0 + tid];
    invs[tid] = 1.0f / s;
  }

  auto stage = [&](int i, int kt, int buf) {
    const int s = i * 512 + tid;          // 16B slot; row stride = 8 slots
    const int row = s >> 3;
    const int cb = (s & 7) << 4;
    const int scb = cb ^ ((row & 7) << 4);
    const f16* src = (row < 64)
        ? e1 + (size_t)(m0 + row) * CNK + kbase + kt * 64 + (scb >> 1)
        : posTb + (size_t)(row - 64) * CNK + kbase + kt * 64 + (scb >> 1);
    async16(src, &sm[buf * (128 * 64) + s * 8]);
  };

  // att0 in-loop writer mapping: row = tid>>3 (64 rows), c = tid&7 (8 col-blocks)
  const int bb = m0 >> 11, nloc = m0 & (CNQ - 1);
  float* attb = att + ((size_t)(bb << 1) * CNQ + nloc) * CNK + kbase;
  const int arow = tid >> 3, acb = tid & 7;

  f32x4 acc[2] = {};
  const int NTk = 16;                    // K = 1024, BK = 64
#pragma unroll
  for (int i = 0; i < 2; i++) stage(i, 0, 0);

  for (int t = 0; t < NTk; ++t) {
    const int cur = t & 1;
    if (t + 1 < NTk) {
#pragma unroll
      for (int i = 0; i < 2; i++) stage(i, t + 1, cur ^ 1);
      asm volatile("s_waitcnt vmcnt(2)" ::: "memory");
    } else {
      asm volatile("s_waitcnt vmcnt(0)" ::: "memory");
    }
    __builtin_amdgcn_s_barrier();
    const f16* smA = sm + cur * (128 * 64);
    const f16* smB = smA + 64 * 64;
#pragma unroll
    for (int kk = 0; kk < 2; ++kk) {
      const int Cb = kk * 64 + kg * 16;
      const int ar = wr * 16 + lrow;
      f16x8 af = *reinterpret_cast<const f16x8*>(
          &smA[ar * 64 + ((Cb ^ ((ar & 7) << 4)) >> 1)]);
#pragma unroll
      for (int n = 0; n < 2; ++n) {
        const int br = wc * 32 + n * 16 + lrow;
        f16x8 bf = *reinterpret_cast<const f16x8*>(
            &smB[br * 64 + ((Cb ^ ((br & 7) << 4)) >> 1)]);
        acc[n] = __builtin_amdgcn_mfma_f32_16x16x32_f16(af, bf, acc[n], 0, 0, 0);
      }
    }
    // att0 write from the staged e1 tile: LDS slot s holds global col block
    // s^(row&7), so global col block c lives at slot c^(row&7).
    {
      const float iv = invs[arow];
      f16x8 v = *reinterpret_cast<const f16x8*>(
          &smA[arow * 64 + ((acb ^ (arow & 7)) << 3)]);
      f32x4 w0 = {(float)v[0] * iv, (float)v[1] * iv, (float)v[2] * iv, (float)v[3] * iv};
      f32x4 w1 = {(float)v[4] * iv, (float)v[5] * iv, (float)v[6] * iv, (float)v[7] * iv};
      float* ap = attb + (size_t)arow * CNK + t * 64 + acb * 8;
      *reinterpret_cast<f32x4*>(ap)     = w0;
      *reinterpret_cast<f32x4*>(ap + 4) = w1;
    }
    __builtin_amdgcn_s_barrier();
  }

  // xw write (partial for this k-half)
  float* Cp = xw + (size_t)blockIdx.z * (CB * CNQ) * CP;
  const int crow = m0 + wr * 16 + (lane >> 4) * 4;
  const int ccol = wc * 32 + (lane & 15);
#pragma unroll
  for (int n = 0; n < 2; n++)
#pragma unroll
    for (int r = 0; r < 4; r++)
      Cp[(size_t)(crow + r) * CP + ccol + n * 16] = acc[n][r];
}

// ---------- attn2 (16 rows/block, 8-way j-split, 2 blocks/CU, padded LDS):
//            x'=(x*inv1)@Wp+bp; e=exp(x'.pos^T/8); att head-1 + e2 ----------
__global__ __launch_bounds__(512) void attn2_kernel(
    const float* __restrict__ xw, const float* __restrict__ Wp,
    const float* __restrict__ bp, const f16* __restrict__ posb,
    const float* __restrict__ PS, f16* __restrict__ e2,
    float* __restrict__ att) {
  // e2lds [16][ELD] f16 (ELD=2056: 4-row group bank shift, 16B aligned);
  // xpb [16][64]; xs (4KB f32) + Wps (16KB f32) alias e2lds head.
  constexpr int ELD = 2056;
  __shared__ __attribute__((aligned(16))) f16 shm[16 * ELD + 16 * 64];
  __shared__ float rsum8[8][16];
  __shared__ float invs[16];
  f16* e2lds = shm;
  f16* xpb = shm + 16 * ELD;
  float* xs = (float*)shm;              // [16][64]
  float* Wps = (float*)shm + 16 * 64;   // [64][64], ends at 20KB < 64KB
  const int tid = threadIdx.x, l = tid & 63, w = tid >> 6;   // w 0..7
  const int r0 = blockIdx.x * 16;
  if (tid < 16) {
    float s = 0.f;
#pragma unroll
    for (int j = 0; j < 8; j++) s += PS[j * (CB * CNQ) + r0 + tid];
    invs[tid] = 1.0f / s;
  }
  __syncthreads();
  if (w < 2) {
#pragma unroll
    for (int i = 0; i < 8; i++) {
      const int row = w * 8 + i;
      const size_t gi = (size_t)(r0 + row) * CP + l;
      xs[row * 64 + l] = (xw[gi] + xw[(size_t)(CB * CNQ) * CP + gi]) * invs[row];
    }
#pragma unroll
    for (int i = w; i < 64; i += 2) Wps[i * 64 + l] = Wp[i * 64 + l];
  }
  const float bpl = bp[l];
  __syncthreads();
  if (w < 2) {
#pragma unroll 2
    for (int i = 0; i < 8; i++) {
      const int row = w * 8 + i;
      float a = bpl;
#pragma unroll 8
      for (int p = 0; p < 64; p++) a = fmaf(xs[row * 64 + p], Wps[p * 64 + l], a);
      xpb[row * 64 + l] = (f16)a;
    }
  }
  __syncthreads();                       // xpb ready; xs/Wps dead -> e2lds free
  const f16x8 af0 = *reinterpret_cast<const f16x8*>(&xpb[(l & 15) * 64 + (l >> 4) * 8]);
  const f16x8 af1 = *reinterpret_cast<const f16x8*>(&xpb[(l & 15) * 64 + 32 + (l >> 4) * 8]);
  float rs[4] = {0.f, 0.f, 0.f, 0.f};
  for (int jt = w * 4; jt < w * 4 + 4; jt++) {   // 8-way j split
#pragma unroll
    for (int q4 = 0; q4 < 4; q4++) {
      const int j = jt * 64 + q4 * 16 + (l & 15);
      const f16* pp = posb + (size_t)j * CP + (l >> 4) * 8;
      f16x8 b0 = *reinterpret_cast<const f16x8*>(pp);
      f16x8 b1 = *reinterpret_cast<const f16x8*>(pp + 32);
      f32x4 c = {};
      c = __builtin_amdgcn_mfma_f32_16x16x32_f16(af0, b0, c, 0, 0, 0);
      c = __builtin_amdgcn_mfma_f32_16x16x32_f16(af1, b1, c, 0, 0, 0);
#pragma unroll
      for (int r = 0; r < 4; r++) {
        float ev = __expf(c[r] * 0.125f);
        rs[r] += ev;
        e2lds[((l >> 4) * 4 + r) * ELD + j] = (f16)ev;
      }
    }
  }
#pragma unroll
  for (int r = 0; r < 4; r++) {
#pragma unroll
    for (int o = 1; o < 16; o <<= 1) rs[r] += __shfl_xor(rs[r], o);
    if ((l & 15) == 0) rsum8[w][(l >> 4) * 4 + r] = rs[r];
  }
  __syncthreads();
  const int b = r0 >> 11, nloc = r0 & (CNQ - 1);
  float* attb = att + ((size_t)((b << 1) + 1) * CNQ + nloc) * CNK;
  f16* e2b = e2 + (size_t)r0 * CNK;
  // 512 threads: 4 rows per iteration, 128 threads per row, 4 iterations
  for (int it = 0; it < 4; it++) {
    const int row = it * 4 + (tid >> 7);
    const int col = (tid & 127) * 16;
    float s = 0.f;
#pragma unroll
    for (int h = 0; h < 8; h++) s += rsum8[h][row];
    const float iv = 1.0f / s;
    const f16x8 a0 = *reinterpret_cast<const f16x8*>(&e2lds[row * ELD + col]);
    const f16x8 a1 = *reinterpret_cast<const f16x8*>(&e2lds[row * ELD + col + 8]);
    f32x4 w0 = {(float)a0[0] * iv, (float)a0[1] * iv, (float)a0[2] * iv, (float)a0[3] * iv};
    f32x4 w1 = {(float)a0[4] * iv, (float)a0[5] * iv, (float)a0[6] * iv, (float)a0[7] * iv};
    f32x4 w2 = {(float)a1[0] * iv, (float)a1[1] * iv, (float)a1[2] * iv, (float)a1[3] * iv};
    f32x4 w3 = {(float)a1[4] * iv, (float)a1[5] * iv, (float)a1[6] * iv, (float)a1[7] * iv};
    float* ap = attb + (size_t)row * CNK + col;
    *reinterpret_cast<f32x4*>(ap)      = w0;
    *reinterpret_cast<f32x4*>(ap + 4)  = w1;
    *reinterpret_cast<f32x4*>(ap + 8)  = w2;
    *reinterpret_cast<f32x4*>(ap + 12) = w3;
    f16x8 h0 = {(f16)w0[0], (f16)w0[1], (f16)w0[2], (f16)w0[3],
                (f16)w1[0], (f16)w1[1], (f16)w1[2], (f16)w1[3]};
    f16x8 h1 = {(f16)w2[0], (f16)w2[1], (f16)w2[2], (f16)w2[3],
                (f16)w3[0], (f16)w3[1], (f16)w3[2], (f16)w3[3]};
    f16* ep = e2b + (size_t)row * CNK + col;
    *reinterpret_cast<f16x8*>(ep)     = h0;
    *reinterpret_cast<f16x8*>(ep + 8) = h1;
  }
}

extern "C" void kernel_launch(void* const* d_in, const int* in_sizes, int n_in,
                              void* d_out, int out_size, void* d_ws, size_t ws_size,
                              hipStream_t stream) {
  (void)in_sizes; (void)n_in; (void)out_size; (void)ws_size;
  const float* q    = (const float*)d_in[0];
  const float* k    = (const float*)d_in[1];
  const float* Wq   = (const float*)d_in[2];
  const float* bq   = (const float*)d_in[3];
  const float* Wk   = (const float*)d_in[4];
  const float* bk   = (const float*)d_in[5];
  const float* Wv   = (const float*)d_in[6];
  const float* bv   = (const float*)d_in[7];
  const float* gq   = (const float*)d_in[8];
  const float* betaq= (const float*)d_in[9];
  const float* gk   = (const float*)d_in[10];
  const float* betak= (const float*)d_in[11];
  const float* gv   = (const float*)d_in[12];
  const float* betav= (const float*)d_in[13];
  const float* Wp   = (const float*)d_in[14];
  const float* bp   = (const float*)d_in[15];

  float* out = (float*)d_out;
  float* att = out + (size_t)CB * CNQ * CD;   // [B,2,NQ,NK]
  char* ws = (char*)d_ws;
  const size_t MB = 1ull << 20;

  f16* q16   = (f16*)(ws);                     // 0-16MB, dead after gemmIn
  f16* k16   = (f16*)(ws + 16 * MB);           // 16-32, dead after gemmIn
  f16* e1    = (f16*)(ws);                     // 0-32 (after q16/k16 die)
  f16* e2    = (f16*)(ws);                     // 0-32 (after e1 dies)
  f16* WqT   = (f16*)(ws + 32 * MB);           // 2MB
  f16* WkvT  = (f16*)(ws + 34 * MB);           // 4MB
  f16* posb  = (f16*)(ws + 38 * MB);           // 256KB
  f16* posTb = (f16*)(ws + 38 * MB + 256 * 1024);
  float* xw  = (float*)(ws + 38 * MB + 512 * 1024); // 4MB [2][8192][64]
  float* PS  = (float*)(ws + 42 * MB + 512 * 1024); // 256KB [8][8192]
  float* vstat = (float*)(ws + 42 * MB + 768 * 1024); // 64KB [2][8192]
  f16* tmpq  = (f16*)(ws + 43 * MB);           // 16MB (qn in place)
  f16* tmp2  = (f16*)(ws + 59 * MB);           // 32MB (kn in place | v raw)
  f16* vnT   = (f16*)(ws + 91 * MB);           // 16MB (ends 107MB)
  f16* qn = tmpq;
  f16* kn = tmp2;            // ld 2048, cols 0-1023

  prep_kernel<<<512 + 16384 + 768, 256, 0, stream>>>(
      q, k, Wq, Wk, Wv, q16, k16, WqT, WkvT, posb, posTb);

  gemmIn_kernel<<<768, 512, 0, stream>>>(q16, WqT, tmpq, k16, WkvT, tmp2);
  ln3_kernel<<<dim3(CB * CNQ, 3), 256, 0, stream>>>(
      tmpq, tmp2, vstat, bq, gq, betaq, bk, gk, betak, bv);
  transposeLN_kernel<<<dim3(CNK / 64, CD / 64, CB), 256, 0, stream>>>(
      tmp2, vnT, vstat, bv, gv, betav);

  gemmS1_kernel<<<256, 512, 0, stream>>>(qn, kn, e1, PS);

  xgemm_kernel<<<dim3(CB * CNQ / 64, 1, 2), 512, 0, stream>>>(e1, posTb, PS, xw, att);
  attn2_kernel<<<CB * CNQ / 16, 512, 0, stream>>>(xw, Wp, bp, posb, PS, e2, att);

  gemmOut_kernel<<<256, 512, 0, stream>>>(e2, vnT, out);
}